// Round 6
// baseline (489.048 us; speedup 1.0000x reference)
//
#include <hip/hip_runtime.h>

#define D 256
#define KCODES 8192
#define NTOK 16384
#define QSIZE (NTOK * D)
#define NBLK 128              // screening blocks of 64 codes
#define CBS 64
// TH: candidate window. Budget (fp16 screen, cb pre-scaled 2^12 so no fp16
// subnormals): ref-rounding eta <= 3.05e-5 + 2*fp16-dot err (max-stat) ~2.4e-5
// + bf16 quantization ~4e-6 => delta ~5.9e-5, need TH >= 2*delta ~1.2e-4.
// TH = 2e-4 gives ~1.7x margin. Used identically for (a) block flagging and
// (b) the decided-gap test (both need TH >= 2*delta). Validated R4/R5.
#define TH 2e-4f
#define CBSCALE 4096.0f       // exact pow2; acc = 2^12 * dot
#define UNSCALE2 4.8828125e-4f // 2^-11 = 2 * 2^-12 (exact)
#define CCAP 4096             // per-nb candidate capacity

typedef _Float16 f16x8 __attribute__((ext_vector_type(8)));  // 8 fp16, 4 VGPRs
typedef float f32x4 __attribute__((ext_vector_type(4)));

#define P2_LDS (256 * 65 * 4)           // 66560 B: cb^T fp32 [256][65]

__device__ __forceinline__ ushort f32_to_bf16(float f) {
    unsigned u = __float_as_uint(f);
    return (ushort)((u + 0x7FFFu + ((u >> 16) & 1)) >> 16);
}
__device__ __forceinline__ float bf16_to_f32(ushort h) {
    return __uint_as_float((unsigned)h << 16);
}
__device__ __forceinline__ ushort f32_to_f16(float f) {
    _Float16 h = (_Float16)f;          // v_cvt_f16_f32, RNE
    ushort u; __builtin_memcpy(&u, &h, 2);
    return u;
}
// race-free broadcast: v_readlane_b32 (register file, exec-independent)
__device__ __forceinline__ float rdlane(float v, int lane) {
    return __uint_as_float(__builtin_amdgcn_readlane(__float_as_uint(v), lane));
}

// ---- fused prep: x -> fp16 + ||x||^2 ; cb -> ||e||^2 ; zero counts ----
// Role split by blockIdx: [0,4096) = x-part (identical indexing/values to
// the R5 cvtx), [4096,6144) = e2-part (identical to R5 e2_kernel).
__global__ __launch_bounds__(256) void prep_kernel(
    const float* __restrict__ x, ushort* __restrict__ xb,
    float* __restrict__ xsq, const float* __restrict__ cb,
    float* __restrict__ e2, unsigned* __restrict__ counts) {
    const int bid = blockIdx.x;
    const int tid = threadIdx.x;
    if (bid == 0 && tid < NBLK) counts[tid] = 0;
    if (bid < 4096) {
        int i = bid * 256 + tid;                 // float4 index
        float4 v = reinterpret_cast<const float4*>(x)[i];
        ushort4 o;
        o.x = f32_to_f16(v.x); o.y = f32_to_f16(v.y);
        o.z = f32_to_f16(v.z); o.w = f32_to_f16(v.w);
        reinterpret_cast<ushort4*>(xb)[i] = o;
        float s = v.x * v.x + v.y * v.y + v.z * v.z + v.w * v.w;
#pragma unroll
        for (int off = 32; off > 0; off >>= 1) s += __shfl_down(s, off);
        if ((tid & 63) == 0) xsq[i >> 6] = s;
    } else {
        int c = (bid - 4096) * 4 + (tid >> 6);
        int lane = tid & 63;
        float4 v = reinterpret_cast<const float4*>(cb + (size_t)c * D)[lane];
        float s = v.x * v.x + v.y * v.y + v.z * v.z + v.w * v.w;
#pragma unroll
        for (int off = 32; off > 0; off >>= 1) s += __shfl_down(s, off);
        if (lane == 0) e2[c] = s;
    }
}

// ---- Pass 1: fp16 MFMA screening GEMM, barrier-free A-from-global ----
// Grid (8 token-chunks, 128 code-blocks). Block: B tile [64 codes][256 k]
// fp16 (32 KB LDS, XOR-swizzled sw = slot ^ (row&7)) converted ONCE from cb
// fp32 (same mul+cvt ops as R5 => identical fp16 bits). A-fragments are
// per-lane-private (no cross-lane reuse) so they load STRAIGHT from xb
// global (16 rows x 64 B contiguous segments per wave, L2-hot) — no A-LDS,
// and therefore NO barriers in the K-loop (single barrier after B-convert).
// MFMA chain per (token, code): same fragments, same mt->nt->ascending-kt
// order as R4/R5 => acc and screen bits unchanged. Epilogue R5-verbatim.
__global__ __launch_bounds__(256, 4) void pass1_kernel(
    const ushort* __restrict__ xb, const float* __restrict__ cb,
    const float* __restrict__ e2, unsigned* __restrict__ screen) {
    __shared__ ushort Bsh[64 * 256];    // 32 KB, swizzled
    const int tid = threadIdx.x;
    const int w = tid >> 6, l = tid & 63;
    const int nb = blockIdx.y;          // 64-code block = nb64 directly
    const int n0 = nb * 64;
    const int tc0 = blockIdx.x * 2048;  // token chunk

    // ---- one-time B conversion: 2048 16B-chunks, 8 per thread ----
#pragma unroll
    for (int j = 0; j < 8; ++j) {
        int c = tid + j * 256;
        int row = c >> 5, slot = c & 31;
        const float4* grow = reinterpret_cast<const float4*>(cb + (size_t)(n0 + row) * D);
        float4 f0 = grow[slot * 2];
        float4 f1 = grow[slot * 2 + 1];
        uint4 q;
        q.x = (unsigned)f32_to_f16(f0.x * CBSCALE) |
              ((unsigned)f32_to_f16(f0.y * CBSCALE) << 16);
        q.y = (unsigned)f32_to_f16(f0.z * CBSCALE) |
              ((unsigned)f32_to_f16(f0.w * CBSCALE) << 16);
        q.z = (unsigned)f32_to_f16(f1.x * CBSCALE) |
              ((unsigned)f32_to_f16(f1.y * CBSCALE) << 16);
        q.w = (unsigned)f32_to_f16(f1.z * CBSCALE) |
              ((unsigned)f32_to_f16(f1.w * CBSCALE) << 16);
        int sw = slot ^ (row & 7);
        *reinterpret_cast<uint4*>(Bsh + row * 256 + sw * 8) = q;
    }
    __syncthreads();                    // the ONLY barrier in this kernel

    const int qh = l >> 4, l7 = l & 7, lm = l & 15;
    // B read: row = nt*16+lm, global slot kt*4+qh, LDS slot ^ (row&7)=^l7.
    // Bank-pos = ((kt*4+qh)^l7)&7: per 16-lane group all 8 positions 2x ->
    // conflict-free. A read: per-lane 16B at xb[row(lane)][kt*32+qh*8].
    const ushort* Bbase = Bsh + lm * 256;
    float e2v[4];
#pragma unroll
    for (int nt = 0; nt < 4; ++nt)
        e2v[nt] = e2[n0 + nt * 16 + lm];

    for (int tt = 0; tt < 8; ++tt) {
        const int tbase = tc0 + tt * 256 + w * 64;   // this wave's 64 tokens
        const ushort* At0 = xb + (size_t)(tbase + lm) * D + qh * 8;
        const ushort* At1 = At0 + 16 * D;
        const ushort* At2 = At0 + 32 * D;
        const ushort* At3 = At0 + 48 * D;
        f32x4 acc[4][4];
#pragma unroll
        for (int mt = 0; mt < 4; ++mt)
#pragma unroll
            for (int nt = 0; nt < 4; ++nt) acc[mt][nt] = (f32x4)0.f;
#pragma unroll
        for (int kt = 0; kt < 8; ++kt) {
            f16x8 a[4], b[4];
            a[0] = *reinterpret_cast<const f16x8*>(At0 + kt * 32);
            a[1] = *reinterpret_cast<const f16x8*>(At1 + kt * 32);
            a[2] = *reinterpret_cast<const f16x8*>(At2 + kt * 32);
            a[3] = *reinterpret_cast<const f16x8*>(At3 + kt * 32);
#pragma unroll
            for (int nt = 0; nt < 4; ++nt)
                b[nt] = *reinterpret_cast<const f16x8*>(
                    Bbase + nt * 4096 + (((kt * 4 + qh) ^ l7) << 3));
#pragma unroll
            for (int mt = 0; mt < 4; ++mt)
#pragma unroll
                for (int nt = 0; nt < 4; ++nt)
                    acc[mt][nt] = __builtin_amdgcn_mfma_f32_16x16x32_f16(
                        a[mt], b[nt], acc[mt][nt], 0, 0, 0);
        }
        // epilogue (R5-verbatim): within-block top-2 + argmin ->
        // screen = m1_bf16<<16 | arg6<<1 | (m2 - m1 > TH).
#pragma unroll
        for (int mt = 0; mt < 4; ++mt) {
#pragma unroll
            for (int r = 0; r < 4; ++r) {
                float v1 = fmaf(-UNSCALE2, acc[mt][0][r], e2v[0]);
                float v2 = 3.4e38f;
                int a1 = lm;
#pragma unroll
                for (int nt = 1; nt < 4; ++nt) {
                    float f = fmaf(-UNSCALE2, acc[mt][nt][r], e2v[nt]);
                    int idx = nt * 16 + lm;
                    bool lt = f < v1;
                    v2 = lt ? v1 : fminf(v2, f);
                    a1 = lt ? idx : a1;
                    v1 = lt ? f : v1;
                }
#pragma unroll
                for (int off = 1; off < 16; off <<= 1) {
                    float ov1 = __shfl_xor(v1, off);
                    float ov2 = __shfl_xor(v2, off);
                    int oa1 = __shfl_xor(a1, off);
                    float nv2 = fminf(fminf(v2, ov2), fmaxf(v1, ov1));
                    bool take = ov1 < v1;
                    v1 = take ? ov1 : v1;
                    a1 = take ? oa1 : a1;
                    v2 = nv2;
                }
                if (lm == 0) {
                    int token = tbase + mt * 16 + (l >> 4) * 4 + r;
                    ushort m1b = f32_to_bf16(v1);
                    unsigned big = (v2 - bf16_to_f32(m1b) > TH) ? 1u : 0u;
                    screen[(size_t)token * NBLK + nb] =
                        ((unsigned)m1b << 16) | ((unsigned)a1 << 1) | big;
                }
            }
        }
    }
}

// ---- Pass 2a: wave-per-token global top-2 over 128 block-mins ----
// (R4/R5 verbatim.) Decided tokens write bestKey directly; ambiguous tokens
// appended to per-nb candidate lists (same criterion as all prior rounds).
__global__ __launch_bounds__(256) void pass2a_kernel(
    const unsigned* __restrict__ screen, unsigned long long* __restrict__ bestKey,
    unsigned* __restrict__ cand, unsigned* __restrict__ counts,
    float* __restrict__ out) {
    const int tid = threadIdx.x;
    const int w = tid >> 6, l = tid & 63;
    const int token = blockIdx.x * 4 + w;
    if (blockIdx.x == 0 && tid == 0) out[(size_t)QSIZE + NTOK] = 0.f;

    uint2 u2 = reinterpret_cast<const uint2*>(screen + (size_t)token * NBLK)[l];
    float ma = bf16_to_f32((ushort)(u2.x >> 16));
    float mb = bf16_to_f32((ushort)(u2.y >> 16));
    float v1, v2; unsigned pk; int blk;
    if (mb < ma) { v1 = mb; v2 = ma; pk = u2.y; blk = 2 * l + 1; }
    else         { v1 = ma; v2 = mb; pk = u2.x; blk = 2 * l; }
#pragma unroll
    for (int off = 1; off < 64; off <<= 1) {
        float ov1 = __shfl_xor(v1, off);
        float ov2 = __shfl_xor(v2, off);
        unsigned opk = __shfl_xor(pk, off);
        int oblk = __shfl_xor(blk, off);
        float nv2 = fminf(fminf(v2, ov2), fmaxf(v1, ov1));
        bool take = ov1 < v1;              // tie -> v2==v1 -> undecided
        v1 = take ? ov1 : v1;
        pk = take ? opk : pk;
        blk = take ? oblk : blk;
        v2 = nv2;
    }
    bool decided = ((pk & 1u) != 0u) && (v2 - v1 > TH);
    if (l == 0)
        bestKey[token] = decided
            ? (unsigned long long)(unsigned)(blk * 64 + (int)((pk >> 1) & 63u))
            : 0xFFFFFFFFFFFFFFFFULL;
    if (!decided) {
        float thr = v1 + TH;
        if (ma <= thr) {
            unsigned s = atomicAdd(&counts[2 * l], 1u);
            if (s < CCAP) cand[(size_t)(2 * l) * CCAP + s] = (unsigned)token;
        }
        if (mb <= thr) {
            unsigned s = atomicAdd(&counts[2 * l + 1], 1u);
            if (s < CCAP) cand[(size_t)(2 * l + 1) * CCAP + s] = (unsigned)token;
        }
    }
}

// ---- Pass 2b: exact fp32-chain rescan of compacted candidates ----
// (R3/R4/R5 verbatim — proven numerics: single fma chain k=0..255,
// v_readlane broadcast, shfl-xor tie-break smallest index, atomicMin.)
__global__ __launch_bounds__(256, 2) void pass2b_kernel(
    const float* __restrict__ x, const float* __restrict__ cb,
    const float* __restrict__ e2, const float* __restrict__ xsq,
    const unsigned* __restrict__ cand, const unsigned* __restrict__ counts,
    unsigned long long* __restrict__ bestKey) {
    extern __shared__ float csh[];          // [256][65] cb^T fp32
    const int tid = threadIdx.x;
    const int nb = blockIdx.x >> 2;         // 64-code block
    const int quarter = blockIdx.x & 3;
    int cnt = (int)counts[nb];
    if (cnt > CCAP) cnt = CCAP;
    if (quarter * 16 >= cnt) return;        // block-uniform, pre-staging

#pragma unroll
    for (int r = 0; r < 16; ++r) {
        int i = r * 256 + tid;
        int row = i >> 6, kq = i & 63;
        float4 v = reinterpret_cast<const float4*>(cb + (size_t)(nb * CBS + row) * D)[kq];
        csh[(kq * 4 + 0) * 65 + row] = v.x;
        csh[(kq * 4 + 1) * 65 + row] = v.y;
        csh[(kq * 4 + 2) * 65 + row] = v.z;
        csh[(kq * 4 + 3) * 65 + row] = v.w;
    }
    __syncthreads();                        // last barrier in this kernel

    const int w = tid >> 6, j = tid & 63;
    const float e2v = e2[nb * CBS + j];
    const int ci0 = nb * CBS + j;
    const float4* X4 = reinterpret_cast<const float4*>(x);
    const unsigned* clist = cand + (size_t)nb * CCAP;
    const int slot = quarter * 4 + w;       // 0..15 sweep slots per nb
    const int p0 = slot * 4;
    if (p0 >= cnt) return;                  // wave-uniform; no barriers follow

    for (int p = p0; p < cnt; p += 64) {
        int i1 = p + 1 < cnt ? p + 1 : cnt - 1;  // tail: replicate (idempotent)
        int i2 = p + 2 < cnt ? p + 2 : cnt - 1;
        int i3 = p + 3 < cnt ? p + 3 : cnt - 1;
        int t0 = (int)clist[p],  t1 = (int)clist[i1];
        int t2 = (int)clist[i2], t3 = (int)clist[i3];
        float4 v0 = X4[(size_t)t0 * 64 + j];
        float4 v1 = X4[(size_t)t1 * 64 + j];
        float4 v2 = X4[(size_t)t2 * 64 + j];
        float4 v3 = X4[(size_t)t3 * 64 + j];
        float a0 = 0.f, a1 = 0.f, a2 = 0.f, a3 = 0.f;
#pragma unroll
        for (int kq = 0; kq < 64; ++kq) {
            float c0 = csh[(kq * 4 + 0) * 65 + j];
            float c1 = csh[(kq * 4 + 1) * 65 + j];
            float c2 = csh[(kq * 4 + 2) * 65 + j];
            float c3 = csh[(kq * 4 + 3) * 65 + j];
            a0 = fmaf(rdlane(v0.x, kq), c0, a0);
            a0 = fmaf(rdlane(v0.y, kq), c1, a0);
            a0 = fmaf(rdlane(v0.z, kq), c2, a0);
            a0 = fmaf(rdlane(v0.w, kq), c3, a0);
            a1 = fmaf(rdlane(v1.x, kq), c0, a1);
            a1 = fmaf(rdlane(v1.y, kq), c1, a1);
            a1 = fmaf(rdlane(v1.z, kq), c2, a1);
            a1 = fmaf(rdlane(v1.w, kq), c3, a1);
            a2 = fmaf(rdlane(v2.x, kq), c0, a2);
            a2 = fmaf(rdlane(v2.y, kq), c1, a2);
            a2 = fmaf(rdlane(v2.z, kq), c2, a2);
            a2 = fmaf(rdlane(v2.w, kq), c3, a2);
            a3 = fmaf(rdlane(v3.x, kq), c0, a3);
            a3 = fmaf(rdlane(v3.y, kq), c1, a3);
            a3 = fmaf(rdlane(v3.z, kq), c2, a3);
            a3 = fmaf(rdlane(v3.w, kq), c3, a3);
        }
        float av[4] = {a0, a1, a2, a3};
        int tv[4] = {t0, t1, t2, t3};
#pragma unroll
        for (int g = 0; g < 4; ++g) {
            float dd = fmaf(-2.f, av[g], xsq[tv[g]] + e2v);
            int ci = ci0;
#pragma unroll
            for (int off = 1; off < 64; off <<= 1) {
                float od = __shfl_xor(dd, off);
                int oc = __shfl_xor(ci, off);
                if (od < dd || (od == dd && oc < ci)) { dd = od; ci = oc; }
            }
            if (j == 0) {
                unsigned u = __float_as_uint(dd);
                u = (u & 0x80000000u) ? ~u : (u | 0x80000000u);
                unsigned long long key =
                    ((unsigned long long)u << 32) | (unsigned)ci;
                atomicMin(bestKey + tv[g], key);   // non-returning: no stall
            }
        }
    }
}

// ---- Pass 3: gather codebook row, emit quantized + idx + partial loss ----
__global__ __launch_bounds__(256) void gather_kernel(
    const float* __restrict__ x, const float* __restrict__ cb,
    const unsigned long long* __restrict__ bestKey,
    float* __restrict__ out, float* __restrict__ partial) {
    __shared__ float red[4];
    const int token = blockIdx.x;
    const int tid = threadIdx.x;
    int idx = (int)(bestKey[token] & 0xFFFFFFFFULL);
    if ((unsigned)idx >= (unsigned)KCODES) idx = 0;  // defensive: no OOB access
    float q = cb[(size_t)idx * D + tid];
    float xv = x[(size_t)token * D + tid];
    out[(size_t)token * D + tid] = q;
    float d = q - xv;
    d = d * d;
#pragma unroll
    for (int off = 32; off > 0; off >>= 1) d += __shfl_down(d, off);
    if ((tid & 63) == 0) red[tid >> 6] = d;
    __syncthreads();
    if (tid == 0) {
        partial[token] = red[0] + red[1] + red[2] + red[3];
        out[(size_t)QSIZE + token] = (float)idx;
    }
}

__global__ __launch_bounds__(256) void loss_kernel(const float* __restrict__ partial,
                                                   float* __restrict__ out) {
    __shared__ float red[4];
    int gid = blockIdx.x * 256 + threadIdx.x;
    float s = partial[gid];
#pragma unroll
    for (int off = 32; off > 0; off >>= 1) s += __shfl_down(s, off);
    if ((threadIdx.x & 63) == 0) red[threadIdx.x >> 6] = s;
    __syncthreads();
    if (threadIdx.x == 0) {
        float total = red[0] + red[1] + red[2] + red[3];
        atomicAdd(out + (size_t)QSIZE + NTOK, 0.25f * total / (float)QSIZE);
    }
}

extern "C" void kernel_launch(void* const* d_in, const int* in_sizes, int n_in,
                              void* d_out, int out_size, void* d_ws, size_t ws_size,
                              hipStream_t stream) {
    const float* x = (const float*)d_in[0];     // [16384, 256]
    const float* cb = (const float*)d_in[1];    // [8192, 256]
    float* out = (float*)d_out;
    float* ws = (float*)d_ws;

    // d_out scratch map (all regions dead before gather overwrites them):
    //   [0, 8M):  xb fp16 (pass1 A-in) -> cand u32 [128][4096] (2 MB; pass2a
    //             writes AFTER pass1 done; stream-ordered)
    //   [8M,16M): screen u32 [NTOK][128] (pass1 out, pass2a in)
    ushort* xb = (ushort*)d_out;
    unsigned* screen = (unsigned*)((char*)d_out + 8388608);
    unsigned* cand = (unsigned*)d_out;

    // ws (floats): e2[8192] | xsq[16384] | counts u32[128] | partial[16384]
    //              @ +8192+2*16384 | bestKey u64 @ +8192+3*16384
    float* e2 = ws;
    float* xsq = ws + 8192;
    unsigned* counts = (unsigned*)(ws + 8192 + 16384);
    float* partial = ws + 8192 + 2 * 16384;
    unsigned long long* bestKey = (unsigned long long*)(ws + 8192 + 3 * 16384);

    hipFuncSetAttribute((const void*)pass2b_kernel,
                        hipFuncAttributeMaxDynamicSharedMemorySize, P2_LDS);

    prep_kernel<<<4096 + KCODES / 4, 256, 0, stream>>>(x, xb, xsq, cb, e2, counts);
    pass1_kernel<<<dim3(8, NBLK), 256, 0, stream>>>(xb, cb, e2, screen);
    pass2a_kernel<<<NTOK / 4, 256, 0, stream>>>(screen, bestKey, cand, counts, out);
    pass2b_kernel<<<4 * NBLK, 256, P2_LDS, stream>>>(
        x, cb, e2, xsq, cand, counts, bestKey);
    gather_kernel<<<NTOK, 256, 0, stream>>>(x, cb, bestKey, out, partial);
    loss_kernel<<<NTOK / 256, 256, 0, stream>>>(partial, out);
}

// Round 8
// 379.913 us; speedup vs baseline: 1.2873x; 1.2873x over previous
//
#include <hip/hip_runtime.h>

#define D 256
#define KCODES 8192
#define NTOK 16384
#define QSIZE (NTOK * D)
#define NBLK 128              // screening blocks of 64 codes
#define CBS 64
// TH: candidate window. Budget (fp16 screen, cb pre-scaled 2^12 so no fp16
// subnormals): ref-rounding eta <= 3.05e-5 + 2*fp16-dot err (max-stat) ~2.4e-5
// + bf16 quantization ~4e-6 => delta ~5.9e-5, need TH >= 2*delta ~1.2e-4.
// TH = 2e-4 gives ~1.7x margin. Used identically for (a) block flagging and
// (b) the decided-gap test (both need TH >= 2*delta). Validated R4/R5/R6.
#define TH 2e-4f
#define CBSCALE 4096.0f       // exact pow2; acc = 2^12 * dot
#define UNSCALE2 4.8828125e-4f // 2^-11 = 2 * 2^-12 (exact)
#define CCAP 4096             // per-nb candidate capacity

typedef _Float16 f16x8 __attribute__((ext_vector_type(8)));  // 8 fp16, 4 VGPRs
typedef float f32x4 __attribute__((ext_vector_type(4)));
typedef __attribute__((address_space(3))) void* lds_vp;
typedef __attribute__((address_space(1))) const void* gbl_vp;

#define P1_LDS (128 * 256 * 2 + 2 * 128 * 32 * 2)   // B 64 KB + A dbuf 16 KB
#define P2_LDS (256 * 65 * 4)                       // 66560 B: cb^T fp32 [256][65]

__device__ __forceinline__ ushort f32_to_bf16(float f) {
    unsigned u = __float_as_uint(f);
    return (ushort)((u + 0x7FFFu + ((u >> 16) & 1)) >> 16);
}
__device__ __forceinline__ float bf16_to_f32(ushort h) {
    return __uint_as_float((unsigned)h << 16);
}
__device__ __forceinline__ ushort f32_to_f16(float f) {
    _Float16 h = (_Float16)f;          // v_cvt_f16_f32, RNE
    ushort u; __builtin_memcpy(&u, &h, 2);
    return u;
}
// race-free broadcast: v_readlane_b32 (register file, exec-independent)
__device__ __forceinline__ float rdlane(float v, int lane) {
    return __uint_as_float(__builtin_amdgcn_readlane(__float_as_uint(v), lane));
}

// ---- fused prep: x -> fp16 + ||x||^2 ; cb -> ||e||^2 ; zero counts ----
// (R6 verbatim — validated.)
__global__ __launch_bounds__(256) void prep_kernel(
    const float* __restrict__ x, ushort* __restrict__ xb,
    float* __restrict__ xsq, const float* __restrict__ cb,
    float* __restrict__ e2, unsigned* __restrict__ counts) {
    const int bid = blockIdx.x;
    const int tid = threadIdx.x;
    if (bid == 0 && tid < NBLK) counts[tid] = 0;
    if (bid < 4096) {
        int i = bid * 256 + tid;                 // float4 index
        float4 v = reinterpret_cast<const float4*>(x)[i];
        ushort4 o;
        o.x = f32_to_f16(v.x); o.y = f32_to_f16(v.y);
        o.z = f32_to_f16(v.z); o.w = f32_to_f16(v.w);
        reinterpret_cast<ushort4*>(xb)[i] = o;
        float s = v.x * v.x + v.y * v.y + v.z * v.z + v.w * v.w;
#pragma unroll
        for (int off = 32; off > 0; off >>= 1) s += __shfl_down(s, off);
        if ((tid & 63) == 0) xsq[i >> 6] = s;
    } else {
        int c = (bid - 4096) * 4 + (tid >> 6);
        int lane = tid & 63;
        float4 v = reinterpret_cast<const float4*>(cb + (size_t)c * D)[lane];
        float s = v.x * v.x + v.y * v.y + v.z * v.z + v.w * v.w;
#pragma unroll
        for (int off = 32; off > 0; off >>= 1) s += __shfl_down(s, off);
        if (lane == 0) e2[c] = s;
    }
}

// ---- Pass 1: fp16 MFMA screening GEMM, B-resident (R5 VERBATIM) ----
// Proven: 166 us, FETCH 37 MB, passed. Grid (8 token-chunks, 64 code-tiles).
// Each block converts its B-tile ONCE (cb fp32 -> fp16*CBSCALE, RNE) into a
// resident 64 KB LDS tile (XOR-swizzled), streams 16 A-tiles via
// global_load_lds double-buffer (source pre-swizzled). MFMA: 8 chained
// 16x16x32 ascending-kt per (token,code) -> acc bits identical to R4/R5/R6.
__global__ __launch_bounds__(256, 2) void pass1_kernel(
    const ushort* __restrict__ xb, const float* __restrict__ cb,
    const float* __restrict__ e2, unsigned* __restrict__ screen) {
    extern __shared__ ushort sm[];
    ushort* Bsh = sm;                    // [128][256] swizzled
    ushort* Ash = sm + 128 * 256;        // [2][128][32] source-swizzled
    const int tid = threadIdx.x;
    const int w = tid >> 6, l = tid & 63;
    const int wr = w >> 1, wc = w & 1;
    const int n0 = blockIdx.y * 128;
    const int tc0 = blockIdx.x * (NTOK / 8);   // 2048 tokens = 16 tiles

    // ---- one-time B conversion: 4096 16B-chunks, 16 per thread ----
#pragma unroll
    for (int j = 0; j < 16; ++j) {
        int c = tid + j * 256;
        int row = c >> 5, slot = c & 31;
        const float4* grow = reinterpret_cast<const float4*>(cb + (size_t)(n0 + row) * D);
        float4 f0 = grow[slot * 2];
        float4 f1 = grow[slot * 2 + 1];
        uint4 q;
        q.x = (unsigned)f32_to_f16(f0.x * CBSCALE) |
              ((unsigned)f32_to_f16(f0.y * CBSCALE) << 16);
        q.y = (unsigned)f32_to_f16(f0.z * CBSCALE) |
              ((unsigned)f32_to_f16(f0.w * CBSCALE) << 16);
        q.z = (unsigned)f32_to_f16(f1.x * CBSCALE) |
              ((unsigned)f32_to_f16(f1.y * CBSCALE) << 16);
        q.w = (unsigned)f32_to_f16(f1.z * CBSCALE) |
              ((unsigned)f32_to_f16(f1.w * CBSCALE) << 16);
        int sw = slot ^ (row & 7);
        *reinterpret_cast<uint4*>(Bsh + row * 256 + sw * 8) = q;
    }

    // A staging geometry: wave w covers tile rows [w*32, w*32+32) via two
    // 1 KB wave-loads; lane l -> LDS (row, l&3), global slot (l&3)^((l>>3)&3).
    const int arow0 = w * 32 + (l >> 2);
    const int arow1 = arow0 + 16;
    const int asg8 = (((l & 3) ^ ((l >> 3) & 3)) << 3);   // short offset

#define STAGE_A(TB, KT, BUF)                                                               \
    do {                                                                                   \
        __builtin_amdgcn_global_load_lds(                                                  \
            (gbl_vp)(xb + (size_t)((TB) + arow0) * D + (KT) * 32 + asg8),                  \
            (lds_vp)(Ash + (BUF) * 4096 + w * 1024), 16, 0, 0);                            \
        __builtin_amdgcn_global_load_lds(                                                  \
            (gbl_vp)(xb + (size_t)((TB) + arow1) * D + (KT) * 32 + asg8),                  \
            (lds_vp)(Ash + (BUF) * 4096 + w * 1024 + 512), 16, 0, 0);                      \
    } while (0)

    // read-side constants
    const int qh = l >> 4, l7 = l & 7;
    const int aslot = qh ^ (((l & 15) >> 1) & 3);
    const int arow_rd = (wr * 64 + (l & 15)) * 32 + aslot * 8;   // + mt*512, + buf*4096
    const int brow_rd = (wc * 64 + (l & 15)) * 256;              // + nt*4096

    float e2v[4];
#pragma unroll
    for (int nt = 0; nt < 4; ++nt)
        e2v[nt] = e2[n0 + wc * 64 + nt * 16 + (l & 15)];
    const int nb64 = blockIdx.y * 2 + wc;

    STAGE_A(tc0, 0, 0);
    __syncthreads();                    // B conversion + first A tile ready

    for (int tt = 0; tt < 16; ++tt) {
        const int tbase = tc0 + tt * 128;
        f32x4 acc[4][4];
#pragma unroll
        for (int mt = 0; mt < 4; ++mt)
#pragma unroll
            for (int nt = 0; nt < 4; ++nt) acc[mt][nt] = (f32x4)0.f;
#pragma unroll
        for (int kt = 0; kt < 8; ++kt) {
            const int cur = kt & 1;     // steps/tile = 8 (even) -> parity by kt
            if (kt < 7) STAGE_A(tbase, kt + 1, cur ^ 1);
            else if (tt < 15) STAGE_A(tbase + 128, 0, cur ^ 1);
            const ushort* abase = Ash + cur * 4096 + arow_rd;
            f16x8 a[4], b[4];
#pragma unroll
            for (int mt = 0; mt < 4; ++mt)
                a[mt] = *reinterpret_cast<const f16x8*>(abase + mt * 512);
#pragma unroll
            for (int nt = 0; nt < 4; ++nt)
                b[nt] = *reinterpret_cast<const f16x8*>(
                    Bsh + brow_rd + nt * 4096 + (((kt * 4 + qh) ^ l7) << 3));
#pragma unroll
            for (int mt = 0; mt < 4; ++mt)
#pragma unroll
                for (int nt = 0; nt < 4; ++nt)
                    acc[mt][nt] = __builtin_amdgcn_mfma_f32_16x16x32_f16(
                        a[mt], b[nt], acc[mt][nt], 0, 0, 0);
            if (kt == 7) {
                // epilogue (R4-verbatim): within-block top-2 + argmin ->
                // screen = m1_bf16<<16 | arg6<<1 | (m2 - m1 > TH).
#pragma unroll
                for (int mt = 0; mt < 4; ++mt) {
#pragma unroll
                    for (int r = 0; r < 4; ++r) {
                        float v1 = fmaf(-UNSCALE2, acc[mt][0][r], e2v[0]);
                        float v2 = 3.4e38f;
                        int a1 = (l & 15);
#pragma unroll
                        for (int nt = 1; nt < 4; ++nt) {
                            float f = fmaf(-UNSCALE2, acc[mt][nt][r], e2v[nt]);
                            int idx = nt * 16 + (l & 15);
                            bool lt = f < v1;
                            v2 = lt ? v1 : fminf(v2, f);
                            a1 = lt ? idx : a1;
                            v1 = lt ? f : v1;
                        }
#pragma unroll
                        for (int off = 1; off < 16; off <<= 1) {
                            float ov1 = __shfl_xor(v1, off);
                            float ov2 = __shfl_xor(v2, off);
                            int oa1 = __shfl_xor(a1, off);
                            float nv2 = fminf(fminf(v2, ov2), fmaxf(v1, ov1));
                            bool take = ov1 < v1;
                            v1 = take ? ov1 : v1;
                            a1 = take ? oa1 : a1;
                            v2 = nv2;
                        }
                        if ((l & 15) == 0) {
                            int token = tbase + wr * 64 + mt * 16 + (l >> 4) * 4 + r;
                            ushort m1b = f32_to_bf16(v1);
                            unsigned big = (v2 - bf16_to_f32(m1b) > TH) ? 1u : 0u;
                            screen[(size_t)token * NBLK + nb64] =
                                ((unsigned)m1b << 16) | ((unsigned)a1 << 1) | big;
                        }
                    }
                }
            }
            __syncthreads();            // prefetch drained + buf reuse-safe
        }
    }
#undef STAGE_A
}

// ---- Pass 2a: wave-per-token global top-2 over 128 block-mins ----
// (R4/R5/R6 verbatim.) Decided tokens write bestKey directly; ambiguous
// tokens appended to per-nb candidate lists.
__global__ __launch_bounds__(256) void pass2a_kernel(
    const unsigned* __restrict__ screen, unsigned long long* __restrict__ bestKey,
    unsigned* __restrict__ cand, unsigned* __restrict__ counts,
    float* __restrict__ out) {
    const int tid = threadIdx.x;
    const int w = tid >> 6, l = tid & 63;
    const int token = blockIdx.x * 4 + w;
    if (blockIdx.x == 0 && tid == 0) out[(size_t)QSIZE + NTOK] = 0.f;

    uint2 u2 = reinterpret_cast<const uint2*>(screen + (size_t)token * NBLK)[l];
    float ma = bf16_to_f32((ushort)(u2.x >> 16));
    float mb = bf16_to_f32((ushort)(u2.y >> 16));
    float v1, v2; unsigned pk; int blk;
    if (mb < ma) { v1 = mb; v2 = ma; pk = u2.y; blk = 2 * l + 1; }
    else         { v1 = ma; v2 = mb; pk = u2.x; blk = 2 * l; }
#pragma unroll
    for (int off = 1; off < 64; off <<= 1) {
        float ov1 = __shfl_xor(v1, off);
        float ov2 = __shfl_xor(v2, off);
        unsigned opk = __shfl_xor(pk, off);
        int oblk = __shfl_xor(blk, off);
        float nv2 = fminf(fminf(v2, ov2), fmaxf(v1, ov1));
        bool take = ov1 < v1;              // tie -> v2==v1 -> undecided
        v1 = take ? ov1 : v1;
        pk = take ? opk : pk;
        blk = take ? oblk : blk;
        v2 = nv2;
    }
    bool decided = ((pk & 1u) != 0u) && (v2 - v1 > TH);
    if (l == 0)
        bestKey[token] = decided
            ? (unsigned long long)(unsigned)(blk * 64 + (int)((pk >> 1) & 63u))
            : 0xFFFFFFFFFFFFFFFFULL;
    if (!decided) {
        float thr = v1 + TH;
        if (ma <= thr) {
            unsigned s = atomicAdd(&counts[2 * l], 1u);
            if (s < CCAP) cand[(size_t)(2 * l) * CCAP + s] = (unsigned)token;
        }
        if (mb <= thr) {
            unsigned s = atomicAdd(&counts[2 * l + 1], 1u);
            if (s < CCAP) cand[(size_t)(2 * l + 1) * CCAP + s] = (unsigned)token;
        }
    }
}

// ---- Pass 2b: exact fp32-chain rescan of compacted candidates ----
// (R3..R6 verbatim — proven numerics: single fma chain k=0..255, v_readlane
// broadcast, shfl-xor tie-break smallest index, packed-key atomicMin.)
__global__ __launch_bounds__(256, 2) void pass2b_kernel(
    const float* __restrict__ x, const float* __restrict__ cb,
    const float* __restrict__ e2, const float* __restrict__ xsq,
    const unsigned* __restrict__ cand, const unsigned* __restrict__ counts,
    unsigned long long* __restrict__ bestKey) {
    extern __shared__ float csh[];          // [256][65] cb^T fp32
    const int tid = threadIdx.x;
    const int nb = blockIdx.x >> 2;         // 64-code block
    const int quarter = blockIdx.x & 3;
    int cnt = (int)counts[nb];
    if (cnt > CCAP) cnt = CCAP;
    if (quarter * 16 >= cnt) return;        // block-uniform, pre-staging

#pragma unroll
    for (int r = 0; r < 16; ++r) {
        int i = r * 256 + tid;
        int row = i >> 6, kq = i & 63;
        float4 v = reinterpret_cast<const float4*>(cb + (size_t)(nb * CBS + row) * D)[kq];
        csh[(kq * 4 + 0) * 65 + row] = v.x;
        csh[(kq * 4 + 1) * 65 + row] = v.y;
        csh[(kq * 4 + 2) * 65 + row] = v.z;
        csh[(kq * 4 + 3) * 65 + row] = v.w;
    }
    __syncthreads();                        // last barrier in this kernel

    const int w = tid >> 6, j = tid & 63;
    const float e2v = e2[nb * CBS + j];
    const int ci0 = nb * CBS + j;
    const float4* X4 = reinterpret_cast<const float4*>(x);
    const unsigned* clist = cand + (size_t)nb * CCAP;
    const int slot = quarter * 4 + w;       // 0..15 sweep slots per nb
    const int p0 = slot * 4;
    if (p0 >= cnt) return;                  // wave-uniform; no barriers follow

    for (int p = p0; p < cnt; p += 64) {
        int i1 = p + 1 < cnt ? p + 1 : cnt - 1;  // tail: replicate (idempotent)
        int i2 = p + 2 < cnt ? p + 2 : cnt - 1;
        int i3 = p + 3 < cnt ? p + 3 : cnt - 1;
        int t0 = (int)clist[p],  t1 = (int)clist[i1];
        int t2 = (int)clist[i2], t3 = (int)clist[i3];
        float4 v0 = X4[(size_t)t0 * 64 + j];
        float4 v1 = X4[(size_t)t1 * 64 + j];
        float4 v2 = X4[(size_t)t2 * 64 + j];
        float4 v3 = X4[(size_t)t3 * 64 + j];
        float a0 = 0.f, a1 = 0.f, a2 = 0.f, a3 = 0.f;
#pragma unroll
        for (int kq = 0; kq < 64; ++kq) {
            float c0 = csh[(kq * 4 + 0) * 65 + j];
            float c1 = csh[(kq * 4 + 1) * 65 + j];
            float c2 = csh[(kq * 4 + 2) * 65 + j];
            float c3 = csh[(kq * 4 + 3) * 65 + j];
            a0 = fmaf(rdlane(v0.x, kq), c0, a0);
            a0 = fmaf(rdlane(v0.y, kq), c1, a0);
            a0 = fmaf(rdlane(v0.z, kq), c2, a0);
            a0 = fmaf(rdlane(v0.w, kq), c3, a0);
            a1 = fmaf(rdlane(v1.x, kq), c0, a1);
            a1 = fmaf(rdlane(v1.y, kq), c1, a1);
            a1 = fmaf(rdlane(v1.z, kq), c2, a1);
            a1 = fmaf(rdlane(v1.w, kq), c3, a1);
            a2 = fmaf(rdlane(v2.x, kq), c0, a2);
            a2 = fmaf(rdlane(v2.y, kq), c1, a2);
            a2 = fmaf(rdlane(v2.z, kq), c2, a2);
            a2 = fmaf(rdlane(v2.w, kq), c3, a2);
            a3 = fmaf(rdlane(v3.x, kq), c0, a3);
            a3 = fmaf(rdlane(v3.y, kq), c1, a3);
            a3 = fmaf(rdlane(v3.z, kq), c2, a3);
            a3 = fmaf(rdlane(v3.w, kq), c3, a3);
        }
        float av[4] = {a0, a1, a2, a3};
        int tv[4] = {t0, t1, t2, t3};
#pragma unroll
        for (int g = 0; g < 4; ++g) {
            float dd = fmaf(-2.f, av[g], xsq[tv[g]] + e2v);
            int ci = ci0;
#pragma unroll
            for (int off = 1; off < 64; off <<= 1) {
                float od = __shfl_xor(dd, off);
                int oc = __shfl_xor(ci, off);
                if (od < dd || (od == dd && oc < ci)) { dd = od; ci = oc; }
            }
            if (j == 0) {
                unsigned u = __float_as_uint(dd);
                u = (u & 0x80000000u) ? ~u : (u | 0x80000000u);
                unsigned long long key =
                    ((unsigned long long)u << 32) | (unsigned)ci;
                atomicMin(bestKey + tv[g], key);   // non-returning: no stall
            }
        }
    }
}

// ---- Pass 3: gather + fused loss. 2048 blocks x 8 tokens. Per-thread
// accumulates d^2 across its 8 tokens (same dim), ONE block reduction, ONE
// atomicAdd into the pass2a-zeroed loss slot (atomic-order summation already
// validated R4-R6). Emits quantized rows + idx as before.
__global__ __launch_bounds__(256) void gather_kernel(
    const float* __restrict__ x, const float* __restrict__ cb,
    const unsigned long long* __restrict__ bestKey,
    float* __restrict__ out) {
    __shared__ float red[4];
    const int tid = threadIdx.x;
    float acc = 0.f;
#pragma unroll
    for (int i = 0; i < 8; ++i) {
        const int token = blockIdx.x * 8 + i;
        int idx = (int)(bestKey[token] & 0xFFFFFFFFULL);
        if ((unsigned)idx >= (unsigned)KCODES) idx = 0;  // defensive
        float q = cb[(size_t)idx * D + tid];
        float xv = x[(size_t)token * D + tid];
        out[(size_t)token * D + tid] = q;
        float d = q - xv;
        acc += d * d;
        if (tid == 0) out[(size_t)QSIZE + token] = (float)idx;
    }
#pragma unroll
    for (int off = 32; off > 0; off >>= 1) acc += __shfl_down(acc, off);
    if ((tid & 63) == 0) red[tid >> 6] = acc;
    __syncthreads();
    if (tid == 0) {
        float total = red[0] + red[1] + red[2] + red[3];
        atomicAdd(out + (size_t)QSIZE + NTOK, 0.25f * total / (float)QSIZE);
    }
}

extern "C" void kernel_launch(void* const* d_in, const int* in_sizes, int n_in,
                              void* d_out, int out_size, void* d_ws, size_t ws_size,
                              hipStream_t stream) {
    const float* x = (const float*)d_in[0];     // [16384, 256]
    const float* cb = (const float*)d_in[1];    // [8192, 256]
    float* out = (float*)d_out;
    float* ws = (float*)d_ws;

    // d_out scratch map (all regions dead before gather overwrites them):
    //   [0, 8M):  xb fp16 (pass1 A-in) -> cand u32 [128][4096] (2 MB; pass2a
    //             writes AFTER pass1 done; stream-ordered)
    //   [8M,16M): screen u32 [NTOK][128] (pass1 out, pass2a in)
    ushort* xb = (ushort*)d_out;
    unsigned* screen = (unsigned*)((char*)d_out + 8388608);
    unsigned* cand = (unsigned*)d_out;

    // ws (floats): e2[8192] | xsq[16384] | counts u32[128] | (dead partial
    // slot) | bestKey u64 @ +8192+3*16384   (layout unchanged)
    float* e2 = ws;
    float* xsq = ws + 8192;
    unsigned* counts = (unsigned*)(ws + 8192 + 16384);
    unsigned long long* bestKey = (unsigned long long*)(ws + 8192 + 3 * 16384);

    hipFuncSetAttribute((const void*)pass1_kernel,
                        hipFuncAttributeMaxDynamicSharedMemorySize, P1_LDS);
    hipFuncSetAttribute((const void*)pass2b_kernel,
                        hipFuncAttributeMaxDynamicSharedMemorySize, P2_LDS);

    prep_kernel<<<4096 + KCODES / 4, 256, 0, stream>>>(x, xb, xsq, cb, e2, counts);
    pass1_kernel<<<dim3(8, KCODES / 128), 256, P1_LDS, stream>>>(xb, cb, e2, screen);
    pass2a_kernel<<<NTOK / 4, 256, 0, stream>>>(screen, bestKey, cand, counts, out);
    pass2b_kernel<<<4 * NBLK, 256, P2_LDS, stream>>>(
        x, cb, e2, xsq, cand, counts, bestKey);
    gather_kernel<<<NTOK / 8, 256, 0, stream>>>(x, cb, bestKey, out);
}

// Round 9
// 311.966 us; speedup vs baseline: 1.5676x; 1.2178x over previous
//
#include <hip/hip_runtime.h>

#define D 256
#define KCODES 8192
#define NTOK 16384
#define QSIZE (NTOK * D)
#define NBLK 128              // screening blocks of 64 codes
#define CBS 64
// TH: candidate window. Budget (fp16 screen, cb pre-scaled 2^12 so no fp16
// subnormals): ref-rounding eta <= 3.05e-5 + 2*fp16-dot err (max-stat) ~2.4e-5
// + bf16 quantization ~4e-6 => delta ~5.9e-5, need TH >= 2*delta ~1.2e-4.
// TH = 2e-4 gives ~1.7x margin. Used identically for (a) block flagging and
// (b) the decided-gap test (both need TH >= 2*delta). Validated R4/R5/R8.
#define TH 2e-4f
#define CBSCALE 4096.0f       // exact pow2; acc = 2^12 * dot
#define UNSCALE2 4.8828125e-4f // 2^-11 = 2 * 2^-12 (exact)
#define CCAP 4096             // per-nb candidate capacity

typedef _Float16 f16x8 __attribute__((ext_vector_type(8)));  // 8 fp16, 4 VGPRs
typedef float f32x4 __attribute__((ext_vector_type(4)));
typedef __attribute__((address_space(3))) void* lds_vp;
typedef __attribute__((address_space(1))) const void* gbl_vp;

#define P1_LDS (128 * 256 * 2 + 2 * 128 * 32 * 2)   // B 64 KB + A dbuf 16 KB
#define P2_LDS (256 * 65 * 4)                       // 66560 B: cb^T fp32 [256][65]

__device__ __forceinline__ ushort f32_to_bf16(float f) {
    unsigned u = __float_as_uint(f);
    return (ushort)((u + 0x7FFFu + ((u >> 16) & 1)) >> 16);
}
__device__ __forceinline__ float bf16_to_f32(ushort h) {
    return __uint_as_float((unsigned)h << 16);
}
__device__ __forceinline__ ushort f32_to_f16(float f) {
    _Float16 h = (_Float16)f;          // v_cvt_f16_f32, RNE
    ushort u; __builtin_memcpy(&u, &h, 2);
    return u;
}
// race-free broadcast: v_readlane_b32 (register file, exec-independent)
__device__ __forceinline__ float rdlane(float v, int lane) {
    return __uint_as_float(__builtin_amdgcn_readlane(__float_as_uint(v), lane));
}

// ---- fused prep: x -> fp16 + ||x||^2 ; cb -> ||e||^2 ; zero counts ----
// (R6/R8 verbatim — validated.)
__global__ __launch_bounds__(256) void prep_kernel(
    const float* __restrict__ x, ushort* __restrict__ xb,
    float* __restrict__ xsq, const float* __restrict__ cb,
    float* __restrict__ e2, unsigned* __restrict__ counts) {
    const int bid = blockIdx.x;
    const int tid = threadIdx.x;
    if (bid == 0 && tid < NBLK) counts[tid] = 0;
    if (bid < 4096) {
        int i = bid * 256 + tid;                 // float4 index
        float4 v = reinterpret_cast<const float4*>(x)[i];
        ushort4 o;
        o.x = f32_to_f16(v.x); o.y = f32_to_f16(v.y);
        o.z = f32_to_f16(v.z); o.w = f32_to_f16(v.w);
        reinterpret_cast<ushort4*>(xb)[i] = o;
        float s = v.x * v.x + v.y * v.y + v.z * v.z + v.w * v.w;
#pragma unroll
        for (int off = 32; off > 0; off >>= 1) s += __shfl_down(s, off);
        if ((tid & 63) == 0) xsq[i >> 6] = s;
    } else {
        int c = (bid - 4096) * 4 + (tid >> 6);
        int lane = tid & 63;
        float4 v = reinterpret_cast<const float4*>(cb + (size_t)c * D)[lane];
        float s = v.x * v.x + v.y * v.y + v.z * v.z + v.w * v.w;
#pragma unroll
        for (int off = 32; off > 0; off >>= 1) s += __shfl_down(s, off);
        if (lane == 0) e2[c] = s;
    }
}

// ---- Pass 1: fp16 MFMA screening GEMM, B-resident, SWAPPED epilogue ----
// Structure (staging, LDS layout, swizzles, grid) is R8-VERBATIM (proven:
// 167 us, FETCH 37 MB, passed). ONE change: MFMA operands are swapped —
// acc[cm][tn] = mfma(b[cm], a[tn], .) — valid because A/B fragments have
// the identical per-lane layout (row/col = lane&15, k = (lane>>4)*8); the
// result is the bit-identical transposed tile (same dot-product sums, each
// acc element an independent chain). Now D rows = codes, cols = tokens:
// lane (qh=l>>4, lm=l&15) holds, for token tn*16+lm, the 16 codes
// {cm*16 + qh*4 + r}. The top-2+argmin is an IN-LANE 16-value scan (pure
// VALU) + 2-level shfl_xor merge (offsets 16,32) — cross-lane ops per tt
// drop 192 -> 24. Min/2nd-min values exact (fmin associative); ties give
// gap 0 -> undecided -> rescan, so argmin tie order is irrelevant. Screen
// words are value-identical to R8.
__global__ __launch_bounds__(256, 2) void pass1_kernel(
    const ushort* __restrict__ xb, const float* __restrict__ cb,
    const float* __restrict__ e2, unsigned* __restrict__ screen) {
    extern __shared__ ushort sm[];
    ushort* Bsh = sm;                    // [128][256] swizzled
    ushort* Ash = sm + 128 * 256;        // [2][128][32] source-swizzled
    const int tid = threadIdx.x;
    const int w = tid >> 6, l = tid & 63;
    const int wr = w >> 1, wc = w & 1;
    const int n0 = blockIdx.y * 128;
    const int tc0 = blockIdx.x * (NTOK / 8);   // 2048 tokens = 16 tiles

    // ---- one-time B conversion: 4096 16B-chunks, 16 per thread ----
#pragma unroll
    for (int j = 0; j < 16; ++j) {
        int c = tid + j * 256;
        int row = c >> 5, slot = c & 31;
        const float4* grow = reinterpret_cast<const float4*>(cb + (size_t)(n0 + row) * D);
        float4 f0 = grow[slot * 2];
        float4 f1 = grow[slot * 2 + 1];
        uint4 q;
        q.x = (unsigned)f32_to_f16(f0.x * CBSCALE) |
              ((unsigned)f32_to_f16(f0.y * CBSCALE) << 16);
        q.y = (unsigned)f32_to_f16(f0.z * CBSCALE) |
              ((unsigned)f32_to_f16(f0.w * CBSCALE) << 16);
        q.z = (unsigned)f32_to_f16(f1.x * CBSCALE) |
              ((unsigned)f32_to_f16(f1.y * CBSCALE) << 16);
        q.w = (unsigned)f32_to_f16(f1.z * CBSCALE) |
              ((unsigned)f32_to_f16(f1.w * CBSCALE) << 16);
        int sw = slot ^ (row & 7);
        *reinterpret_cast<uint4*>(Bsh + row * 256 + sw * 8) = q;
    }

    // A staging geometry (R8 verbatim): wave w covers tile rows [w*32,+32)
    // via two 1 KB wave-loads; source slot pre-swizzled.
    const int arow0 = w * 32 + (l >> 2);
    const int arow1 = arow0 + 16;
    const int asg8 = (((l & 3) ^ ((l >> 3) & 3)) << 3);   // short offset

#define STAGE_A(TB, KT, BUF)                                                               \
    do {                                                                                   \
        __builtin_amdgcn_global_load_lds(                                                  \
            (gbl_vp)(xb + (size_t)((TB) + arow0) * D + (KT) * 32 + asg8),                  \
            (lds_vp)(Ash + (BUF) * 4096 + w * 1024), 16, 0, 0);                            \
        __builtin_amdgcn_global_load_lds(                                                  \
            (gbl_vp)(xb + (size_t)((TB) + arow1) * D + (KT) * 32 + asg8),                  \
            (lds_vp)(Ash + (BUF) * 4096 + w * 1024 + 512), 16, 0, 0);                      \
    } while (0)

    // read-side constants (R8 verbatim)
    const int qh = l >> 4, l7 = l & 7, lm = l & 15;
    const int aslot = qh ^ ((lm >> 1) & 3);
    const int arow_rd = (wr * 64 + lm) * 32 + aslot * 8;   // + tn*512, + buf*4096
    const int brow_rd = (wc * 64 + lm) * 256;              // + cm*4096

    // e2 for the 16 codes this lane holds: code = cm*16 + qh*4 + r
    float e2v[16];
#pragma unroll
    for (int cm = 0; cm < 4; ++cm)
#pragma unroll
        for (int r = 0; r < 4; ++r)
            e2v[cm * 4 + r] = e2[n0 + wc * 64 + cm * 16 + qh * 4 + r];
    const int nb64 = blockIdx.y * 2 + wc;

    STAGE_A(tc0, 0, 0);
    __syncthreads();                    // B conversion + first A tile ready

    for (int tt = 0; tt < 16; ++tt) {
        const int tbase = tc0 + tt * 128;
        f32x4 acc[4][4];                // [cm][tn]
#pragma unroll
        for (int cm = 0; cm < 4; ++cm)
#pragma unroll
            for (int tn = 0; tn < 4; ++tn) acc[cm][tn] = (f32x4)0.f;
#pragma unroll
        for (int kt = 0; kt < 8; ++kt) {
            const int cur = kt & 1;     // steps/tile = 8 (even) -> parity by kt
            if (kt < 7) STAGE_A(tbase, kt + 1, cur ^ 1);
            else if (tt < 15) STAGE_A(tbase + 128, 0, cur ^ 1);
            const ushort* abase = Ash + cur * 4096 + arow_rd;
            f16x8 a[4], b[4];
#pragma unroll
            for (int tn = 0; tn < 4; ++tn)
                a[tn] = *reinterpret_cast<const f16x8*>(abase + tn * 512);
#pragma unroll
            for (int cm = 0; cm < 4; ++cm)
                b[cm] = *reinterpret_cast<const f16x8*>(
                    Bsh + brow_rd + cm * 4096 + (((kt * 4 + qh) ^ l7) << 3));
#pragma unroll
            for (int cm = 0; cm < 4; ++cm)
#pragma unroll
                for (int tn = 0; tn < 4; ++tn)
                    acc[cm][tn] = __builtin_amdgcn_mfma_f32_16x16x32_f16(
                        b[cm], a[tn], acc[cm][tn], 0, 0, 0);
            if (kt == 7) {
                // SWAPPED epilogue: per token-tile tn, lane holds 16 codes
                // in-register -> in-lane top-2 scan + 2-level qh-merge.
#pragma unroll
                for (int tn = 0; tn < 4; ++tn) {
                    float v1 = fmaf(-UNSCALE2, acc[0][tn][0], e2v[0]);
                    float v2 = 3.4e38f;
                    int a1 = qh * 4;
#pragma unroll
                    for (int q = 1; q < 16; ++q) {
                        const int cm = q >> 2, r = q & 3;
                        float f = fmaf(-UNSCALE2, acc[cm][tn][r], e2v[q]);
                        int idx = cm * 16 + qh * 4 + r;
                        bool lt = f < v1;
                        v2 = lt ? v1 : fminf(v2, f);
                        a1 = lt ? idx : a1;
                        v1 = lt ? f : v1;
                    }
#pragma unroll
                    for (int off = 16; off < 64; off <<= 1) {
                        float ov1 = __shfl_xor(v1, off);
                        float ov2 = __shfl_xor(v2, off);
                        int oa1 = __shfl_xor(a1, off);
                        float nv2 = fminf(fminf(v2, ov2), fmaxf(v1, ov1));
                        bool take = ov1 < v1;     // tie -> gap 0 -> undecided
                        v1 = take ? ov1 : v1;
                        a1 = take ? oa1 : a1;
                        v2 = nv2;
                    }
                    if (qh == 0) {
                        int token = tbase + wr * 64 + tn * 16 + lm;
                        ushort m1b = f32_to_bf16(v1);
                        unsigned big = (v2 - bf16_to_f32(m1b) > TH) ? 1u : 0u;
                        screen[(size_t)token * NBLK + nb64] =
                            ((unsigned)m1b << 16) | ((unsigned)a1 << 1) | big;
                    }
                }
            }
            __syncthreads();            // prefetch drained + buf reuse-safe
        }
    }
#undef STAGE_A
}

// ---- Pass 2a: wave-per-token global top-2 over 128 block-mins ----
// (R4..R8 verbatim.) Decided tokens write bestKey directly; ambiguous
// tokens appended to per-nb candidate lists.
__global__ __launch_bounds__(256) void pass2a_kernel(
    const unsigned* __restrict__ screen, unsigned long long* __restrict__ bestKey,
    unsigned* __restrict__ cand, unsigned* __restrict__ counts,
    float* __restrict__ out) {
    const int tid = threadIdx.x;
    const int w = tid >> 6, l = tid & 63;
    const int token = blockIdx.x * 4 + w;
    if (blockIdx.x == 0 && tid == 0) out[(size_t)QSIZE + NTOK] = 0.f;

    uint2 u2 = reinterpret_cast<const uint2*>(screen + (size_t)token * NBLK)[l];
    float ma = bf16_to_f32((ushort)(u2.x >> 16));
    float mb = bf16_to_f32((ushort)(u2.y >> 16));
    float v1, v2; unsigned pk; int blk;
    if (mb < ma) { v1 = mb; v2 = ma; pk = u2.y; blk = 2 * l + 1; }
    else         { v1 = ma; v2 = mb; pk = u2.x; blk = 2 * l; }
#pragma unroll
    for (int off = 1; off < 64; off <<= 1) {
        float ov1 = __shfl_xor(v1, off);
        float ov2 = __shfl_xor(v2, off);
        unsigned opk = __shfl_xor(pk, off);
        int oblk = __shfl_xor(blk, off);
        float nv2 = fminf(fminf(v2, ov2), fmaxf(v1, ov1));
        bool take = ov1 < v1;              // tie -> v2==v1 -> undecided
        v1 = take ? ov1 : v1;
        pk = take ? opk : pk;
        blk = take ? oblk : blk;
        v2 = nv2;
    }
    bool decided = ((pk & 1u) != 0u) && (v2 - v1 > TH);
    if (l == 0)
        bestKey[token] = decided
            ? (unsigned long long)(unsigned)(blk * 64 + (int)((pk >> 1) & 63u))
            : 0xFFFFFFFFFFFFFFFFULL;
    if (!decided) {
        float thr = v1 + TH;
        if (ma <= thr) {
            unsigned s = atomicAdd(&counts[2 * l], 1u);
            if (s < CCAP) cand[(size_t)(2 * l) * CCAP + s] = (unsigned)token;
        }
        if (mb <= thr) {
            unsigned s = atomicAdd(&counts[2 * l + 1], 1u);
            if (s < CCAP) cand[(size_t)(2 * l + 1) * CCAP + s] = (unsigned)token;
        }
    }
}

// ---- Pass 2b: exact fp32-chain rescan of compacted candidates ----
// (R3..R8 verbatim — proven numerics: single fma chain k=0..255, v_readlane
// broadcast, shfl-xor tie-break smallest index, packed-key atomicMin.)
__global__ __launch_bounds__(256, 2) void pass2b_kernel(
    const float* __restrict__ x, const float* __restrict__ cb,
    const float* __restrict__ e2, const float* __restrict__ xsq,
    const unsigned* __restrict__ cand, const unsigned* __restrict__ counts,
    unsigned long long* __restrict__ bestKey) {
    extern __shared__ float csh[];          // [256][65] cb^T fp32
    const int tid = threadIdx.x;
    const int nb = blockIdx.x >> 2;         // 64-code block
    const int quarter = blockIdx.x & 3;
    int cnt = (int)counts[nb];
    if (cnt > CCAP) cnt = CCAP;
    if (quarter * 16 >= cnt) return;        // block-uniform, pre-staging

#pragma unroll
    for (int r = 0; r < 16; ++r) {
        int i = r * 256 + tid;
        int row = i >> 6, kq = i & 63;
        float4 v = reinterpret_cast<const float4*>(cb + (size_t)(nb * CBS + row) * D)[kq];
        csh[(kq * 4 + 0) * 65 + row] = v.x;
        csh[(kq * 4 + 1) * 65 + row] = v.y;
        csh[(kq * 4 + 2) * 65 + row] = v.z;
        csh[(kq * 4 + 3) * 65 + row] = v.w;
    }
    __syncthreads();                        // last barrier in this kernel

    const int w = tid >> 6, j = tid & 63;
    const float e2v = e2[nb * CBS + j];
    const int ci0 = nb * CBS + j;
    const float4* X4 = reinterpret_cast<const float4*>(x);
    const unsigned* clist = cand + (size_t)nb * CCAP;
    const int slot = quarter * 4 + w;       // 0..15 sweep slots per nb
    const int p0 = slot * 4;
    if (p0 >= cnt) return;                  // wave-uniform; no barriers follow

    for (int p = p0; p < cnt; p += 64) {
        int i1 = p + 1 < cnt ? p + 1 : cnt - 1;  // tail: replicate (idempotent)
        int i2 = p + 2 < cnt ? p + 2 : cnt - 1;
        int i3 = p + 3 < cnt ? p + 3 : cnt - 1;
        int t0 = (int)clist[p],  t1 = (int)clist[i1];
        int t2 = (int)clist[i2], t3 = (int)clist[i3];
        float4 v0 = X4[(size_t)t0 * 64 + j];
        float4 v1 = X4[(size_t)t1 * 64 + j];
        float4 v2 = X4[(size_t)t2 * 64 + j];
        float4 v3 = X4[(size_t)t3 * 64 + j];
        float a0 = 0.f, a1 = 0.f, a2 = 0.f, a3 = 0.f;
#pragma unroll
        for (int kq = 0; kq < 64; ++kq) {
            float c0 = csh[(kq * 4 + 0) * 65 + j];
            float c1 = csh[(kq * 4 + 1) * 65 + j];
            float c2 = csh[(kq * 4 + 2) * 65 + j];
            float c3 = csh[(kq * 4 + 3) * 65 + j];
            a0 = fmaf(rdlane(v0.x, kq), c0, a0);
            a0 = fmaf(rdlane(v0.y, kq), c1, a0);
            a0 = fmaf(rdlane(v0.z, kq), c2, a0);
            a0 = fmaf(rdlane(v0.w, kq), c3, a0);
            a1 = fmaf(rdlane(v1.x, kq), c0, a1);
            a1 = fmaf(rdlane(v1.y, kq), c1, a1);
            a1 = fmaf(rdlane(v1.z, kq), c2, a1);
            a1 = fmaf(rdlane(v1.w, kq), c3, a1);
            a2 = fmaf(rdlane(v2.x, kq), c0, a2);
            a2 = fmaf(rdlane(v2.y, kq), c1, a2);
            a2 = fmaf(rdlane(v2.z, kq), c2, a2);
            a2 = fmaf(rdlane(v2.w, kq), c3, a2);
            a3 = fmaf(rdlane(v3.x, kq), c0, a3);
            a3 = fmaf(rdlane(v3.y, kq), c1, a3);
            a3 = fmaf(rdlane(v3.z, kq), c2, a3);
            a3 = fmaf(rdlane(v3.w, kq), c3, a3);
        }
        float av[4] = {a0, a1, a2, a3};
        int tv[4] = {t0, t1, t2, t3};
#pragma unroll
        for (int g = 0; g < 4; ++g) {
            float dd = fmaf(-2.f, av[g], xsq[tv[g]] + e2v);
            int ci = ci0;
#pragma unroll
            for (int off = 1; off < 64; off <<= 1) {
                float od = __shfl_xor(dd, off);
                int oc = __shfl_xor(ci, off);
                if (od < dd || (od == dd && oc < ci)) { dd = od; ci = oc; }
            }
            if (j == 0) {
                unsigned u = __float_as_uint(dd);
                u = (u & 0x80000000u) ? ~u : (u | 0x80000000u);
                unsigned long long key =
                    ((unsigned long long)u << 32) | (unsigned)ci;
                atomicMin(bestKey + tv[g], key);   // non-returning: no stall
            }
        }
    }
}

// ---- Pass 3: gather + fused loss (R8 verbatim — validated). ----
__global__ __launch_bounds__(256) void gather_kernel(
    const float* __restrict__ x, const float* __restrict__ cb,
    const unsigned long long* __restrict__ bestKey,
    float* __restrict__ out) {
    __shared__ float red[4];
    const int tid = threadIdx.x;
    float acc = 0.f;
#pragma unroll
    for (int i = 0; i < 8; ++i) {
        const int token = blockIdx.x * 8 + i;
        int idx = (int)(bestKey[token] & 0xFFFFFFFFULL);
        if ((unsigned)idx >= (unsigned)KCODES) idx = 0;  // defensive
        float q = cb[(size_t)idx * D + tid];
        float xv = x[(size_t)token * D + tid];
        out[(size_t)token * D + tid] = q;
        float d = q - xv;
        acc += d * d;
        if (tid == 0) out[(size_t)QSIZE + token] = (float)idx;
    }
#pragma unroll
    for (int off = 32; off > 0; off >>= 1) acc += __shfl_down(acc, off);
    if ((tid & 63) == 0) red[tid >> 6] = acc;
    __syncthreads();
    if (tid == 0) {
        float total = red[0] + red[1] + red[2] + red[3];
        atomicAdd(out + (size_t)QSIZE + NTOK, 0.25f * total / (float)QSIZE);
    }
}

extern "C" void kernel_launch(void* const* d_in, const int* in_sizes, int n_in,
                              void* d_out, int out_size, void* d_ws, size_t ws_size,
                              hipStream_t stream) {
    const float* x = (const float*)d_in[0];     // [16384, 256]
    const float* cb = (const float*)d_in[1];    // [8192, 256]
    float* out = (float*)d_out;
    float* ws = (float*)d_ws;

    // d_out scratch map (all regions dead before gather overwrites them):
    //   [0, 8M):  xb fp16 (pass1 A-in) -> cand u32 [128][4096] (2 MB; pass2a
    //             writes AFTER pass1 done; stream-ordered)
    //   [8M,16M): screen u32 [NTOK][128] (pass1 out, pass2a in)
    ushort* xb = (ushort*)d_out;
    unsigned* screen = (unsigned*)((char*)d_out + 8388608);
    unsigned* cand = (unsigned*)d_out;

    // ws (floats): e2[8192] | xsq[16384] | counts u32[128] | (dead partial
    // slot) | bestKey u64 @ +8192+3*16384   (layout unchanged)
    float* e2 = ws;
    float* xsq = ws + 8192;
    unsigned* counts = (unsigned*)(ws + 8192 + 16384);
    unsigned long long* bestKey = (unsigned long long*)(ws + 8192 + 3 * 16384);

    hipFuncSetAttribute((const void*)pass1_kernel,
                        hipFuncAttributeMaxDynamicSharedMemorySize, P1_LDS);
    hipFuncSetAttribute((const void*)pass2b_kernel,
                        hipFuncAttributeMaxDynamicSharedMemorySize, P2_LDS);

    prep_kernel<<<4096 + KCODES / 4, 256, 0, stream>>>(x, xb, xsq, cb, e2, counts);
    pass1_kernel<<<dim3(8, KCODES / 128), 256, P1_LDS, stream>>>(xb, cb, e2, screen);
    pass2a_kernel<<<NTOK / 4, 256, 0, stream>>>(screen, bestKey, cand, counts, out);
    pass2b_kernel<<<4 * NBLK, 256, P2_LDS, stream>>>(
        x, cb, e2, xsq, cand, counts, bestKey);
    gather_kernel<<<NTOK / 8, 256, 0, stream>>>(x, cb, bestKey, out);
}